// Round 11
// baseline (194.428 us; speedup 1.0000x reference)
//
#include <hip/hip_runtime.h>
#include <stdint.h>

// Problem constants (fixed by the reference)
#define BQ   2
#define NQ   8192
#define D1Q  128
#define D2Q  256
#define OUTQ 128
#define CATQ 384   // D1+D2
#define KQ   16

// ---------------------------------------------------------------------------
// Kernel 1: prep = W transpose + xyz1 norms in one launch.
// ---------------------------------------------------------------------------
__global__ void prep_kernel(const float* __restrict__ W, float* __restrict__ Wt,
                            const float* __restrict__ xyz1,
                            float4* __restrict__ xyz1n) {
    int flat = blockIdx.x * 256 + threadIdx.x;
    if (flat < CATQ * OUTQ) {
        int k = flat >> 7;          // / OUTQ
        int o = flat & (OUTQ - 1);
        Wt[flat] = W[o * CATQ + k];
    }
    if (flat < BQ * NQ) {
        float x = xyz1[flat * 3 + 0];
        float y = xyz1[flat * 3 + 1];
        float z = xyz1[flat * 3 + 2];
        float n;
        {
            #pragma clang fp contract(off)
            float px = x * x, py = y * y, pz = z * z;
            n = (px + py) + pz;
        }
        xyz1n[flat] = make_float4(x, y, z, n);
    }
}

__device__ __forceinline__ void fma4(float4& acc, float a, const float4& w) {
    acc.x = fmaf(a, w.x, acc.x);
    acc.y = fmaf(a, w.y, acc.y);
    acc.z = fmaf(a, w.z, acc.z);
    acc.w = fmaf(a, w.w, acc.w);
}

// ---------------------------------------------------------------------------
// Kernel 2 (R11): LDS-staged-W GEMM, 32 rows/block, double-buffered W chunk.
// Thread = 4 rows x 4 cols; block = 32 rows x 128 cols; grid 512 (2/CU).
// Halving wave count (vs R10) halves per-CU W ds_read volume (~10us);
// single barrier per chunk (reg-prefetch -> write other buffer -> barrier).
// Chunk order rotated per block to decorrelate L2 staging reads.
// ---------------------------------------------------------------------------
__global__ __launch_bounds__(256) void proj_kernel(
        const float* __restrict__ points1, const float* __restrict__ points2,
        const float* __restrict__ Wt, const float* __restrict__ bias,
        float* __restrict__ P1Wb, float* __restrict__ P2W) {
    __shared__ __align__(16) float Wl[2][32 * OUTQ];   // 2 x 16 KB W chunks

    const int tid = threadIdx.x;
    const int bid = blockIdx.x;
    const int rg  = tid >> 5;             // 0..7 -> rows rg*4 .. rg*4+3
    const int o0  = (tid & 31) * 4;       // output col base
    const int r0  = bid * 32 + rg * 4;

    // chunk c in [0,12): c<4 -> pass A (points1), else pass B (points2).
    // k-offset within the pass, rotated by bid:
    auto a_off = [&](int c) -> int {
        return (c < 4) ? ((c + bid) & 3) * 32 : (((c - 4) + bid) & 7) * 32;
    };
    auto stage_src = [&](int c) -> const float4* {
        int kg = (c < 4) ? a_off(c) : (D1Q + a_off(c));
        return (const float4*)(Wt + (size_t)kg * OUTQ);
    };

    // prime chunk 0 (1024 float4 staged by 256 threads)
    float4 pre[4];
    {
        const float4* s = stage_src(0);
        #pragma unroll
        for (int i = 0; i < 4; ++i) pre[i] = s[tid + 256 * i];
        #pragma unroll
        for (int i = 0; i < 4; ++i) ((float4*)Wl[0])[tid + 256 * i] = pre[i];
    }
    __syncthreads();

    float4 acc[4];
    #pragma unroll
    for (int i = 0; i < 4; ++i) acc[i] = make_float4(0.f, 0.f, 0.f, 0.f);

    for (int c = 0; c < 12; ++c) {
        if (c + 1 < 12) {                   // global->reg prefetch, next chunk
            const float4* s = stage_src(c + 1);
            #pragma unroll
            for (int i = 0; i < 4; ++i) pre[i] = s[tid + 256 * i];
        }

        const float* Wb = Wl[c & 1];
        const int    ko = a_off(c);
        const float* ar = (c < 4) ? points1 : points2;
        const int    ld = (c < 4) ? D1Q : D2Q;
        const float* a0 = ar + (size_t)(r0 + 0) * ld + ko;
        const float* a1 = ar + (size_t)(r0 + 1) * ld + ko;
        const float* a2 = ar + (size_t)(r0 + 2) * ld + ko;
        const float* a3 = ar + (size_t)(r0 + 3) * ld + ko;

        #pragma unroll
        for (int kk = 0; kk < 8; ++kk) {
            const float* wb = Wb + (kk * 4) * OUTQ + o0;
            float4 w0 = *(const float4*)(wb + 0 * OUTQ);
            float4 w1 = *(const float4*)(wb + 1 * OUTQ);
            float4 w2 = *(const float4*)(wb + 2 * OUTQ);
            float4 w3 = *(const float4*)(wb + 3 * OUTQ);
            float4 av0 = *(const float4*)(a0 + kk * 4);
            float4 av1 = *(const float4*)(a1 + kk * 4);
            float4 av2 = *(const float4*)(a2 + kk * 4);
            float4 av3 = *(const float4*)(a3 + kk * 4);
            fma4(acc[0], av0.x, w0); fma4(acc[0], av0.y, w1);
            fma4(acc[0], av0.z, w2); fma4(acc[0], av0.w, w3);
            fma4(acc[1], av1.x, w0); fma4(acc[1], av1.y, w1);
            fma4(acc[1], av1.z, w2); fma4(acc[1], av1.w, w3);
            fma4(acc[2], av2.x, w0); fma4(acc[2], av2.y, w1);
            fma4(acc[2], av2.z, w2); fma4(acc[2], av2.w, w3);
            fma4(acc[3], av3.x, w0); fma4(acc[3], av3.y, w1);
            fma4(acc[3], av3.z, w2); fma4(acc[3], av3.w, w3);
        }

        if (c == 3) {                       // pass-A boundary
            float4 bv = *(const float4*)(bias + o0);
            #pragma unroll
            for (int i = 0; i < 4; ++i) {
                float4 r = acc[i];
                r.x += bv.x; r.y += bv.y; r.z += bv.z; r.w += bv.w;
                *(float4*)&P1Wb[(size_t)(r0 + i) * OUTQ + o0] = r;
                acc[i] = make_float4(0.f, 0.f, 0.f, 0.f);
            }
        }

        if (c + 1 < 12) {                   // reg->LDS into the other buffer
            #pragma unroll
            for (int i = 0; i < 4; ++i)
                ((float4*)Wl[(c + 1) & 1])[tid + 256 * i] = pre[i];
        }
        __syncthreads();                    // single barrier per chunk
    }

    #pragma unroll
    for (int i = 0; i < 4; ++i)
        *(float4*)&P2W[(size_t)(r0 + i) * OUTQ + o0] = acc[i];
}

// numpy-exact squared distance (same rounding as the reference BLAS path)
__device__ __forceinline__ float npy_d2(float4 pt, float qx, float qy, float qz,
                                        float s2) {
    #pragma clang fp contract(off)
    float d0  = pt.x * qx;                 // rounded product
    float dot = fmaf(pt.y, qy, d0);        // explicit FMA chain
    dot       = fmaf(pt.z, qz, dot);
    float tt  = s2 + pt.w;                 // rounded add
    return tt - 2.0f * dot;                // 2*dot exact; rounded sub
}

// reduced-space proxy: r = n1 - 2*dot ; exact_d2 ~= s2 + r within ~2.3e-5.
// Used ONLY for the conservative filter; keys always use npy_d2.
__device__ __forceinline__ float red_r(float4 pt, float qx, float qy, float qz) {
    float d0  = pt.x * qx;
    float dot = fmaf(pt.y, qy, d0);
    dot       = fmaf(pt.z, qz, dot);
    return fmaf(-2.0f, dot, pt.w);
}

#define RED_MARGIN 2e-4f    // >= 4x worst-case |exact - (s2+r)| bound

// full ascending bitonic sort of one uint64 per lane across the wave
__device__ __forceinline__ uint64_t sort64(uint64_t x, int lane) {
    #pragma unroll
    for (int k = 2; k <= 64; k <<= 1) {
        #pragma unroll
        for (int j = k >> 1; j > 0; j >>= 1) {
            uint64_t p = __shfl_xor((unsigned long long)x, j, 64);
            bool keep_min = (((lane & j) == 0) == ((lane & k) == 0));
            bool pless    = p < x;
            x = (pless == keep_min) ? p : x;   // ties: same value either way
        }
    }
    return x;
}

// ---------------------------------------------------------------------------
// Kernel 3 (R11): fused 16-NN + weights + gather/combine.
// Reduced-dot (4-op) proxy r for phase-1 minima and phase-2 gate; threshold
// t_red = rank15(lane-min r) + RED_MARGIN is provably conservative, so the
// survivor set still contains the true top-16; exact npy_d2 keys (computed
// only on survivor steps) keep the final selection bit-identical.
// ---------------------------------------------------------------------------
__global__ __launch_bounds__(256) void fpn_kernel(
        const float4* __restrict__ xyz1n, const float* __restrict__ xyz2,
        const float* __restrict__ P1Wb, const float* __restrict__ P2W,
        float* __restrict__ out) {
    __shared__ __align__(16) float4 xyzt4[1024];   // 16 KB tile
    __shared__ uint64_t wbuf[16][128];             // 16 KB candidate spill

    const int tid   = threadIdx.x;
    const int lane  = tid & 63;
    const int w     = tid >> 6;
    const int qbase = blockIdx.x * 16 + w * 4;     // wave's 4 queries
    const int b     = (blockIdx.x * 16) >> 13;     // uniform per block

    float qx[4], qy[4], qz[4], s2[4];
    #pragma unroll
    for (int j = 0; j < 4; ++j) {
        const float* qp = xyz2 + (size_t)(qbase + j) * 3;
        qx[j] = qp[0]; qy[j] = qp[1]; qz[j] = qp[2];
        {
            #pragma clang fp contract(off)
            float px = qx[j] * qx[j], py = qy[j] * qy[j], pz = qz[j] * qz[j];
            s2[j] = (px + py) + pz;
        }
    }

    const float4* xb = xyz1n + (size_t)b * NQ;

    // ---------------- Phase 1: reduced-space lane-min scan ----------------
    float mn[4];
    #pragma unroll
    for (int j = 0; j < 4; ++j) mn[j] = __uint_as_float(0x7F800000u);

    for (int tile = 0; tile < 8; ++tile) {
        __syncthreads();
        {
            const float4* s4 = xb + tile * 1024;
            #pragma unroll
            for (int v = tid; v < 1024; v += 256) xyzt4[v] = s4[v];
        }
        __syncthreads();
        #pragma unroll 4
        for (int s = 0; s < 16; ++s) {
            float4 pt = xyzt4[s * 64 + lane];
            #pragma unroll
            for (int j = 0; j < 4; ++j)
                mn[j] = fminf(mn[j], red_r(pt, qx[j], qy[j], qz[j]));
        }
    }

    // 4 float bitonic sorts of lane minima; t_red[j] = rank-15 + margin
    float tred[4];
    #pragma unroll
    for (int j = 0; j < 4; ++j) {
        float x = mn[j];
        #pragma unroll
        for (int k = 2; k <= 64; k <<= 1) {
            #pragma unroll
            for (int jj = k >> 1; jj > 0; jj >>= 1) {
                float px = __shfl_xor(x, jj, 64);
                bool keep_min = (((lane & jj) == 0) == ((lane & k) == 0));
                float mnv = fminf(x, px), mxv = fmaxf(x, px);
                x = keep_min ? mnv : mxv;
            }
        }
        tred[j] = __shfl(x, 15, 64) + RED_MARGIN;
    }

    // ---------------- Phase 2: gated compaction (reduced gate) ----------------
    uint32_t cnt[4] = {0u, 0u, 0u, 0u};
    for (int tt = 0; tt < 8; ++tt) {
        const int tile = 7 - tt;                   // tile 7 still resident
        if (tt > 0) {
            __syncthreads();
            const float4* s4 = xb + tile * 1024;
            #pragma unroll
            for (int v = tid; v < 1024; v += 256) xyzt4[v] = s4[v];
            __syncthreads();
        }
        const uint32_t base = (uint32_t)tile * 1024u;
        #pragma unroll 4
        for (int s = 0; s < 16; ++s) {
            float4 pt = xyzt4[s * 64 + lane];
            const uint32_t pidx = base + (uint32_t)(s * 64 + lane);
            #pragma unroll
            for (int j = 0; j < 4; ++j) {
                float r  = red_r(pt, qx[j], qy[j], qz[j]);
                bool  v  = (r <= tred[j]);
                uint64_t mask = __ballot((int)v);
                if (mask != 0ull) {                // scalar gate, ~20% taken
                    if (v) {
                        // exact key only for survivors
                        float d2 = npy_d2(pt, qx[j], qy[j], qz[j], s2[j]);
                        uint32_t below = __builtin_amdgcn_mbcnt_hi(
                            (uint32_t)(mask >> 32),
                            __builtin_amdgcn_mbcnt_lo((uint32_t)mask, 0u));
                        uint32_t pos    = cnt[j] + below;
                        uint32_t bits   = __float_as_uint(d2);
                        uint32_t mapped = bits ^ (0x80000000u |
                                          (uint32_t)((int32_t)bits >> 31));
                        if (pos < 128u)
                            wbuf[w * 4 + j][pos] =
                                ((uint64_t)mapped << 32) | (uint64_t)pidx;
                    }
                    cnt[j] += (uint32_t)__popcll(mask);
                }
            }
        }
    }

    // ---------------- per-query selection + weights + gather ----------------
    const float* p2b = P2W + (size_t)b * NQ * OUTQ;
    #pragma unroll
    for (int j = 0; j < 4; ++j) {
        const int qi = w * 4 + j;
        const uint32_t c = cnt[j];
        uint64_t mykey;
        if (c <= 64u) {                            // normal path
            uint64_t k0 = (lane < (int)c) ? wbuf[qi][lane] : ~0ull;
            mykey = sort64(k0, lane);
        } else {                                   // uniform fallback
            uint32_t cc = c > 128u ? 128u : c;
            uint64_t k0 = wbuf[qi][lane];
            uint64_t k1 = (lane + 64 < (int)cc) ? wbuf[qi][lane + 64] : ~0ull;
            k0 = sort64(k0, lane);
            k1 = sort64(k1, lane);
            uint64_t t1 = __shfl((unsigned long long)k1, lane & 15, 64);
            uint64_t km = (lane < 16) ? k0 : ((lane < 32) ? t1 : ~0ull);
            mykey = sort64(km, lane);
        }

        // inverse-distance weights (lanes 0..15 hold the 16 NN)
        uint32_t mhi   = (uint32_t)(mykey >> 32);
        uint32_t rbits = (mhi & 0x80000000u) ? (mhi ^ 0x80000000u) : ~mhi;
        float    d2w   = __uint_as_float(rbits);
        int      myidx = (int)(uint32_t)(mykey & 0xFFFFFFFFull);
        float recip = (lane < KQ) ? (1.0f / (d2w + 1e-8f)) : 0.0f;
        float tot = recip;
        #pragma unroll
        for (int sh = 1; sh < 16; sh <<= 1) tot += __shfl_xor(tot, sh, 64);
        float wgt = recip / tot;                   // valid in lanes 0..15

        // gather + combine: out = P1Wb[q] + sum_k w_k * P2W[idx_k]
        const float2* prow = (const float2*)(P1Wb + (size_t)(qbase + j) * OUTQ);
        float2 acc = prow[lane];
        #pragma unroll
        for (int k = 0; k < KQ; ++k) {
            int   kk = __builtin_amdgcn_readlane(myidx, k);
            float wk = __uint_as_float((uint32_t)__builtin_amdgcn_readlane(
                           (int)__float_as_uint(wgt), k));
            const float2 row = *(const float2*)(p2b + (size_t)kk * OUTQ + lane * 2);
            acc.x = fmaf(wk, row.x, acc.x);
            acc.y = fmaf(wk, row.y, acc.y);
        }
        *(float2*)(out + (size_t)(qbase + j) * OUTQ + lane * 2) = acc;
    }
}

// ---------------------------------------------------------------------------
// Launch
// ---------------------------------------------------------------------------
extern "C" void kernel_launch(void* const* d_in, const int* in_sizes, int n_in,
                              void* d_out, int out_size, void* d_ws, size_t ws_size,
                              hipStream_t stream) {
    const float* xyz1    = (const float*)d_in[0];
    const float* xyz2    = (const float*)d_in[1];
    const float* points1 = (const float*)d_in[2];
    const float* points2 = (const float*)d_in[3];
    const float* W       = (const float*)d_in[4];
    const float* bias    = (const float*)d_in[5];

    float* wsf  = (float*)d_ws;
    float* Wt   = wsf;                         // 384*128   = 49152 floats
    float* P1Wb = wsf + 49152;                 // 16384*128 = 2097152 floats
    float* P2W  = P1Wb + 2097152;              // 16384*128
    float4* xyz1n = (float4*)(P2W + 2097152);  // 16384 float4

    prep_kernel<<<192, 256, 0, stream>>>(W, Wt, xyz1, xyz1n);
    proj_kernel<<<(BQ * NQ) / 32, 256, 0, stream>>>(points1, points2, Wt, bias, P1Wb, P2W);
    fpn_kernel<<<(BQ * NQ) / 16, 256, 0, stream>>>(xyz1n, xyz2, P1Wb, P2W, (float*)d_out);
}

// Round 12
// 184.283 us; speedup vs baseline: 1.0551x; 1.0551x over previous
//
#include <hip/hip_runtime.h>
#include <stdint.h>

// Problem constants (fixed by the reference)
#define BQ   2
#define NQ   8192
#define D1Q  128
#define D2Q  256
#define OUTQ 128
#define CATQ 384   // D1+D2
#define KQ   16

// ---------------------------------------------------------------------------
// Kernel 1: prep = W transpose + xyz1 norms (tiny).
// ---------------------------------------------------------------------------
__global__ void prep_kernel(const float* __restrict__ W, float* __restrict__ Wt,
                            const float* __restrict__ xyz1,
                            float4* __restrict__ xyz1n) {
    int flat = blockIdx.x * 256 + threadIdx.x;
    if (flat < CATQ * OUTQ) {
        int k = flat >> 7;          // / OUTQ
        int o = flat & (OUTQ - 1);
        Wt[flat] = W[o * CATQ + k];
    }
    if (flat < BQ * NQ) {
        float x = xyz1[flat * 3 + 0];
        float y = xyz1[flat * 3 + 1];
        float z = xyz1[flat * 3 + 2];
        float n;
        {
            #pragma clang fp contract(off)
            float px = x * x, py = y * y, pz = z * z;
            n = (px + py) + pz;
        }
        xyz1n[flat] = make_float4(x, y, z, n);
    }
}

__device__ __forceinline__ void fma4(float4& acc, float a, const float4& w) {
    acc.x = fmaf(a, w.x, acc.x);
    acc.y = fmaf(a, w.y, acc.y);
    acc.z = fmaf(a, w.z, acc.z);
    acc.w = fmaf(a, w.w, acc.w);
}

// numpy-exact squared distance (same rounding as the reference BLAS path)
__device__ __forceinline__ float npy_d2(float4 pt, float qx, float qy, float qz,
                                        float s2) {
    #pragma clang fp contract(off)
    float d0  = pt.x * qx;                 // rounded product
    float dot = fmaf(pt.y, qy, d0);        // explicit FMA chain
    dot       = fmaf(pt.z, qz, dot);
    float tt  = s2 + pt.w;                 // rounded add
    return tt - 2.0f * dot;                // 2*dot exact; rounded sub
}

// full ascending bitonic sort of one uint64 per lane across the wave
__device__ __forceinline__ uint64_t sort64(uint64_t x, int lane) {
    #pragma unroll
    for (int k = 2; k <= 64; k <<= 1) {
        #pragma unroll
        for (int j = k >> 1; j > 0; j >>= 1) {
            uint64_t p = __shfl_xor((unsigned long long)x, j, 64);
            bool keep_min = (((lane & j) == 0) == ((lane & k) == 0));
            bool pless    = p < x;
            x = (pless == keep_min) ? p : x;   // ties: same value either way
        }
    }
    return x;
}

// ---------------------------------------------------------------------------
// Kernel 2 (R12): FULLY FUSED. Per block: 16 queries.
//  Stage 1 (R8-exact NN): phases 1+2, per-query sort, weights.
//  Stage 2: build cat[16][384] in LDS: cat[:,0:128] = points1 rows;
//           cat[:,128:384] = interp = sum_k w_k * points2[idx_k] (raw gather,
//           k ascending = reference top_k order).
//  Stage 3: block GEMM cat @ Wt (12 LDS-staged 32-k chunks) + bias -> out.
// No inter-block dependencies -> single kernel, no P1Wb/P2W round-trip.
// LDS: NN area (tile 16K + wbuf 16K) UNION GEMM area (cat 24K + Wl 16K) = 40K
// -> 4 blocks/CU, same occupancy as the proven R8 fpn.
// ---------------------------------------------------------------------------
__global__ __launch_bounds__(256, 4) void fused_kernel(
        const float4* __restrict__ xyz1n, const float* __restrict__ xyz2,
        const float* __restrict__ points1, const float* __restrict__ points2,
        const float* __restrict__ Wt, const float* __restrict__ bias,
        float* __restrict__ out) {
    __shared__ __align__(16) char smem[40960];
    float4*   xyzt4 = (float4*)smem;                 // [0,16K)  stage 1
    uint64_t* wball = (uint64_t*)(smem + 16384);     // [16K,32K) stage 1: [16][128]
    float*    cat   = (float*)smem;                  // [0,24K)  stages 2-3
    float*    Wl    = (float*)(smem + 24576);        // [24K,40K) stage 3

    const int tid   = threadIdx.x;
    const int lane  = tid & 63;
    const int w     = tid >> 6;
    const int qbase = blockIdx.x * 16 + w * 4;     // wave's 4 queries
    const int b     = (blockIdx.x * 16) >> 13;     // uniform per block

    float qx[4], qy[4], qz[4], s2[4];
    #pragma unroll
    for (int j = 0; j < 4; ++j) {
        const float* qp = xyz2 + (size_t)(qbase + j) * 3;
        qx[j] = qp[0]; qy[j] = qp[1]; qz[j] = qp[2];
        {
            #pragma clang fp contract(off)
            float px = qx[j] * qx[j], py = qy[j] * qy[j], pz = qz[j] * qz[j];
            s2[j] = (px + py) + pz;
        }
    }

    const float4* xb = xyz1n + (size_t)b * NQ;

    // ---------------- Phase 1 (R8-exact): branchless lane-min scan ----------------
    float mn[4];
    #pragma unroll
    for (int j = 0; j < 4; ++j) mn[j] = __uint_as_float(0x7F800000u);

    for (int tile = 0; tile < 8; ++tile) {
        __syncthreads();
        {
            const float4* s4 = xb + tile * 1024;
            #pragma unroll
            for (int v = tid; v < 1024; v += 256) xyzt4[v] = s4[v];
        }
        __syncthreads();
        #pragma unroll 4
        for (int s = 0; s < 16; ++s) {
            float4 pt = xyzt4[s * 64 + lane];
            #pragma unroll
            for (int j = 0; j < 4; ++j)
                mn[j] = fminf(mn[j], npy_d2(pt, qx[j], qy[j], qz[j], s2[j]));
        }
    }

    // 4 float bitonic sorts of lane minima; that[j] = rank 15 (provably safe)
    float that[4];
    #pragma unroll
    for (int j = 0; j < 4; ++j) {
        float x = mn[j];
        #pragma unroll
        for (int k = 2; k <= 64; k <<= 1) {
            #pragma unroll
            for (int jj = k >> 1; jj > 0; jj >>= 1) {
                float px = __shfl_xor(x, jj, 64);
                bool keep_min = (((lane & jj) == 0) == ((lane & k) == 0));
                float mnv = fminf(x, px), mxv = fmaxf(x, px);
                x = keep_min ? mnv : mxv;
            }
        }
        that[j] = __shfl(x, 15, 64);
    }

    // ---------------- Phase 2 (R8-exact): gated compaction ----------------
    uint32_t cnt[4] = {0u, 0u, 0u, 0u};
    for (int tt = 0; tt < 8; ++tt) {
        const int tile = 7 - tt;                   // tile 7 still resident
        if (tt > 0) {
            __syncthreads();
            const float4* s4 = xb + tile * 1024;
            #pragma unroll
            for (int v = tid; v < 1024; v += 256) xyzt4[v] = s4[v];
            __syncthreads();
        }
        const uint32_t base = (uint32_t)tile * 1024u;
        #pragma unroll 4
        for (int s = 0; s < 16; ++s) {
            float4 pt = xyzt4[s * 64 + lane];
            const uint32_t pidx = base + (uint32_t)(s * 64 + lane);
            #pragma unroll
            for (int j = 0; j < 4; ++j) {
                float d2 = npy_d2(pt, qx[j], qy[j], qz[j], s2[j]);
                bool  v  = (d2 <= that[j]);
                uint64_t mask = __ballot((int)v);
                if (mask != 0ull) {                // scalar gate, ~15% taken
                    if (v) {
                        uint32_t below = __builtin_amdgcn_mbcnt_hi(
                            (uint32_t)(mask >> 32),
                            __builtin_amdgcn_mbcnt_lo((uint32_t)mask, 0u));
                        uint32_t pos    = cnt[j] + below;
                        uint32_t bits   = __float_as_uint(d2);
                        uint32_t mapped = bits ^ (0x80000000u |
                                          (uint32_t)((int32_t)bits >> 31));
                        if (pos < 128u)
                            wball[(w * 4 + j) * 128 + pos] =
                                ((uint64_t)mapped << 32) | (uint64_t)pidx;
                    }
                    cnt[j] += (uint32_t)__popcll(mask);
                }
            }
        }
    }

    // ---------------- per-query selection + weights (R8-exact) ----------------
    int   myidxA[4];
    float mywgtA[4];
    #pragma unroll
    for (int j = 0; j < 4; ++j) {
        const uint64_t* wb = wball + (size_t)(w * 4 + j) * 128;
        const uint32_t c = cnt[j];
        uint64_t mykey;
        if (c <= 64u) {                            // normal path
            uint64_t k0 = (lane < (int)c) ? wb[lane] : ~0ull;
            mykey = sort64(k0, lane);
        } else {                                   // uniform fallback
            uint32_t cc = c > 128u ? 128u : c;
            uint64_t k0 = wb[lane];
            uint64_t k1 = (lane + 64 < (int)cc) ? wb[lane + 64] : ~0ull;
            k0 = sort64(k0, lane);
            k1 = sort64(k1, lane);
            uint64_t t1 = __shfl((unsigned long long)k1, lane & 15, 64);
            uint64_t km = (lane < 16) ? k0 : ((lane < 32) ? t1 : ~0ull);
            mykey = sort64(km, lane);
        }
        uint32_t mhi   = (uint32_t)(mykey >> 32);
        uint32_t rbits = (mhi & 0x80000000u) ? (mhi ^ 0x80000000u) : ~mhi;
        float    d2w   = __uint_as_float(rbits);
        myidxA[j] = (int)(uint32_t)(mykey & 0xFFFFFFFFull);
        float recip = (lane < KQ) ? (1.0f / (d2w + 1e-8f)) : 0.0f;
        float tot = recip;
        #pragma unroll
        for (int sh = 1; sh < 16; sh <<= 1) tot += __shfl_xor(tot, sh, 64);
        mywgtA[j] = recip / tot;                   // valid in lanes 0..15
    }

    // LDS reuse boundary: all waves done with xyzt4 + wbuf
    __syncthreads();

    // ---------------- Stage 2: build cat[16][384] in LDS ----------------
    const float* p2b = points2 + (size_t)b * NQ * D2Q;
    #pragma unroll
    for (int j = 0; j < 4; ++j) {
        const int qi = w * 4 + j;
        // p1 part: 128 floats, lanes 0..31
        if (lane < 32) {
            float4 p = ((const float4*)(points1 + (size_t)(qbase + j) * D1Q))[lane];
            *(float4*)&cat[qi * CATQ + lane * 4] = p;
        }
        // interp part: 256 floats, all 64 lanes; k ascending (reference order)
        float4 acc = make_float4(0.f, 0.f, 0.f, 0.f);
        #pragma unroll
        for (int k = 0; k < KQ; ++k) {
            int   kk = __builtin_amdgcn_readlane(myidxA[j], k);
            float wk = __uint_as_float((uint32_t)__builtin_amdgcn_readlane(
                           (int)__float_as_uint(mywgtA[j]), k));
            float4 row = ((const float4*)(p2b + (size_t)kk * D2Q))[lane];
            acc.x = fmaf(wk, row.x, acc.x);
            acc.y = fmaf(wk, row.y, acc.y);
            acc.z = fmaf(wk, row.z, acc.z);
            acc.w = fmaf(wk, row.w, acc.w);
        }
        *(float4*)&cat[qi * CATQ + D1Q + lane * 4] = acc;
    }
    __syncthreads();

    // ---------------- Stage 3: block GEMM cat @ Wt + bias ----------------
    const int rg = tid >> 5;              // 0..7 -> cat rows rg*2, rg*2+1
    const int o0 = (tid & 31) * 4;        // output col base
    float4 acc0 = make_float4(0.f, 0.f, 0.f, 0.f);
    float4 acc1 = make_float4(0.f, 0.f, 0.f, 0.f);

    for (int c = 0; c < 12; ++c) {
        if (c) __syncthreads();           // protect previous chunk's readers
        {
            const float4* src = (const float4*)(Wt + (size_t)c * 32 * OUTQ);
            #pragma unroll
            for (int i = 0; i < 4; ++i)
                ((float4*)Wl)[tid + 256 * i] = src[tid + 256 * i];
        }
        __syncthreads();

        const int kb = c * 32;
        #pragma unroll
        for (int k4 = 0; k4 < 8; ++k4) {
            const float* wb = Wl + (k4 * 4) * OUTQ + o0;
            float4 w0 = *(const float4*)(wb + 0 * OUTQ);
            float4 w1 = *(const float4*)(wb + 1 * OUTQ);
            float4 w2 = *(const float4*)(wb + 2 * OUTQ);
            float4 w3 = *(const float4*)(wb + 3 * OUTQ);
            float4 a0 = *(const float4*)&cat[(rg * 2 + 0) * CATQ + kb + k4 * 4];
            float4 a1 = *(const float4*)&cat[(rg * 2 + 1) * CATQ + kb + k4 * 4];
            fma4(acc0, a0.x, w0); fma4(acc0, a0.y, w1);
            fma4(acc0, a0.z, w2); fma4(acc0, a0.w, w3);
            fma4(acc1, a1.x, w0); fma4(acc1, a1.y, w1);
            fma4(acc1, a1.z, w2); fma4(acc1, a1.w, w3);
        }
    }

    {
        float4 bv = *(const float4*)(bias + o0);
        acc0.x += bv.x; acc0.y += bv.y; acc0.z += bv.z; acc0.w += bv.w;
        acc1.x += bv.x; acc1.y += bv.y; acc1.z += bv.z; acc1.w += bv.w;
        const int q0 = blockIdx.x * 16 + rg * 2;
        *(float4*)&out[(size_t)(q0 + 0) * OUTQ + o0] = acc0;
        *(float4*)&out[(size_t)(q0 + 1) * OUTQ + o0] = acc1;
    }
}

// ---------------------------------------------------------------------------
// Launch
// ---------------------------------------------------------------------------
extern "C" void kernel_launch(void* const* d_in, const int* in_sizes, int n_in,
                              void* d_out, int out_size, void* d_ws, size_t ws_size,
                              hipStream_t stream) {
    const float* xyz1    = (const float*)d_in[0];
    const float* xyz2    = (const float*)d_in[1];
    const float* points1 = (const float*)d_in[2];
    const float* points2 = (const float*)d_in[3];
    const float* W       = (const float*)d_in[4];
    const float* bias    = (const float*)d_in[5];

    float* wsf  = (float*)d_ws;
    float* Wt   = wsf;                         // 384*128 = 49152 floats
    float4* xyz1n = (float4*)(wsf + 49152);    // 16384 float4

    prep_kernel<<<192, 256, 0, stream>>>(W, Wt, xyz1, xyz1n);
    fused_kernel<<<(BQ * NQ) / 16, 256, 0, stream>>>(
        xyz1n, xyz2, points1, points2, Wt, bias, (float*)d_out);
}

// Round 13
// 178.453 us; speedup vs baseline: 1.0895x; 1.0327x over previous
//
#include <hip/hip_runtime.h>
#include <stdint.h>

// Problem constants (fixed by the reference)
#define BQ   2
#define NQ   8192
#define D1Q  128
#define D2Q  256
#define OUTQ 128
#define CATQ 384   // D1+D2
#define KQ   16

// ---------------------------------------------------------------------------
// Kernel 1: prep = W transpose + xyz1 norms (tiny).
// ---------------------------------------------------------------------------
__global__ void prep_kernel(const float* __restrict__ W, float* __restrict__ Wt,
                            const float* __restrict__ xyz1,
                            float4* __restrict__ xyz1n) {
    int flat = blockIdx.x * 256 + threadIdx.x;
    if (flat < CATQ * OUTQ) {
        int k = flat >> 7;          // / OUTQ
        int o = flat & (OUTQ - 1);
        Wt[flat] = W[o * CATQ + k];
    }
    if (flat < BQ * NQ) {
        float x = xyz1[flat * 3 + 0];
        float y = xyz1[flat * 3 + 1];
        float z = xyz1[flat * 3 + 2];
        float n;
        {
            #pragma clang fp contract(off)
            float px = x * x, py = y * y, pz = z * z;
            n = (px + py) + pz;
        }
        xyz1n[flat] = make_float4(x, y, z, n);
    }
}

__device__ __forceinline__ void fma4(float4& acc, float a, const float4& w) {
    acc.x = fmaf(a, w.x, acc.x);
    acc.y = fmaf(a, w.y, acc.y);
    acc.z = fmaf(a, w.z, acc.z);
    acc.w = fmaf(a, w.w, acc.w);
}

// numpy-exact squared distance (same rounding as the reference BLAS path)
__device__ __forceinline__ float npy_d2(float4 pt, float qx, float qy, float qz,
                                        float s2) {
    #pragma clang fp contract(off)
    float d0  = pt.x * qx;                 // rounded product
    float dot = fmaf(pt.y, qy, d0);        // explicit FMA chain
    dot       = fmaf(pt.z, qz, dot);
    float tt  = s2 + pt.w;                 // rounded add
    return tt - 2.0f * dot;                // 2*dot exact; rounded sub
}

// 4-op reduced proxy: exact_d2 ~= s2 + red within ~1.5e-5 (values O(30)).
// Phase-1 bound only; never used for keys.
__device__ __forceinline__ float red_r(float4 pt, float qx, float qy, float qz) {
    float dot = fmaf(pt.z, qz, fmaf(pt.y, qy, pt.x * qx));
    return fmaf(-2.0f, dot, pt.w);
}
#define RED_MARGIN 1e-3f   // >= 60x the proxy-vs-exact bound

// full ascending bitonic sort of one uint64 per lane across the wave
__device__ __forceinline__ uint64_t sort64(uint64_t x, int lane) {
    #pragma unroll
    for (int k = 2; k <= 64; k <<= 1) {
        #pragma unroll
        for (int j = k >> 1; j > 0; j >>= 1) {
            uint64_t p = __shfl_xor((unsigned long long)x, j, 64);
            bool keep_min = (((lane & j) == 0) == ((lane & k) == 0));
            bool pless    = p < x;
            x = (pless == keep_min) ? p : x;   // ties: same value either way
        }
    }
    return x;
}

// ---------------------------------------------------------------------------
// Kernel 2 (R13): fused NN + interp + GEMM. Per block: 16 queries.
// Changes vs R12 (counters: VALU 82us dominant):
//  - Phase 1 scans HALF the points (tiles 0-3). rank-15 of the 64 lane-minima
//    over ANY 64-distinct-candidate subset upper-bounds the true 16th
//    distance -> still provably safe; survivors grow ~2x (~40-70), far under
//    the 128 cap, and phase-2 cost is survivor-independent.
//  - Phase 1 uses the 4-op reduced proxy; that[j] = s2 + rank15 + RED_MARGIN
//    (margin 60x the proxy error bound). Phase 2 remains branchless and
//    bit-exact (npy_d2 keys, same tie-break) -> selection identical.
// ---------------------------------------------------------------------------
__global__ __launch_bounds__(256, 4) void fused_kernel(
        const float4* __restrict__ xyz1n, const float* __restrict__ xyz2,
        const float* __restrict__ points1, const float* __restrict__ points2,
        const float* __restrict__ Wt, const float* __restrict__ bias,
        float* __restrict__ out) {
    __shared__ __align__(16) char smem[40960];
    float4*   xyzt4 = (float4*)smem;                 // [0,16K)  stage 1
    uint64_t* wball = (uint64_t*)(smem + 16384);     // [16K,32K) stage 1: [16][128]
    float*    cat   = (float*)smem;                  // [0,24K)  stages 2-3
    float*    Wl    = (float*)(smem + 24576);        // [24K,40K) stage 3

    const int tid   = threadIdx.x;
    const int lane  = tid & 63;
    const int w     = tid >> 6;
    const int qbase = blockIdx.x * 16 + w * 4;     // wave's 4 queries
    const int b     = (blockIdx.x * 16) >> 13;     // uniform per block

    float qx[4], qy[4], qz[4], s2[4];
    #pragma unroll
    for (int j = 0; j < 4; ++j) {
        const float* qp = xyz2 + (size_t)(qbase + j) * 3;
        qx[j] = qp[0]; qy[j] = qp[1]; qz[j] = qp[2];
        {
            #pragma clang fp contract(off)
            float px = qx[j] * qx[j], py = qy[j] * qy[j], pz = qz[j] * qz[j];
            s2[j] = (px + py) + pz;
        }
    }

    const float4* xb = xyz1n + (size_t)b * NQ;

    // ------- Phase 1: reduced-proxy lane-min scan over HALF the points -------
    float mn[4];
    #pragma unroll
    for (int j = 0; j < 4; ++j) mn[j] = __uint_as_float(0x7F800000u);

    for (int tile = 0; tile < 4; ++tile) {
        __syncthreads();
        {
            const float4* s4 = xb + tile * 1024;
            #pragma unroll
            for (int v = tid; v < 1024; v += 256) xyzt4[v] = s4[v];
        }
        __syncthreads();
        #pragma unroll 4
        for (int s = 0; s < 16; ++s) {
            float4 pt = xyzt4[s * 64 + lane];
            #pragma unroll
            for (int j = 0; j < 4; ++j)
                mn[j] = fminf(mn[j], red_r(pt, qx[j], qy[j], qz[j]));
        }
    }

    // 4 float bitonic sorts of lane minima; that[j] = s2 + rank15 + margin
    float that[4];
    #pragma unroll
    for (int j = 0; j < 4; ++j) {
        float x = mn[j];
        #pragma unroll
        for (int k = 2; k <= 64; k <<= 1) {
            #pragma unroll
            for (int jj = k >> 1; jj > 0; jj >>= 1) {
                float px = __shfl_xor(x, jj, 64);
                bool keep_min = (((lane & jj) == 0) == ((lane & k) == 0));
                float mnv = fminf(x, px), mxv = fmaxf(x, px);
                x = keep_min ? mnv : mxv;
            }
        }
        that[j] = s2[j] + __shfl(x, 15, 64) + RED_MARGIN;
    }

    // ------- Phase 2 (R12-exact, branchless d2): gated compaction -------
    uint32_t cnt[4] = {0u, 0u, 0u, 0u};
    for (int tt = 0; tt < 8; ++tt) {
        const int tile = (3 + tt) & 7;             // tile 3 still resident
        if (tt > 0) {
            __syncthreads();
            const float4* s4 = xb + tile * 1024;
            #pragma unroll
            for (int v = tid; v < 1024; v += 256) xyzt4[v] = s4[v];
            __syncthreads();
        }
        const uint32_t base = (uint32_t)tile * 1024u;
        #pragma unroll 4
        for (int s = 0; s < 16; ++s) {
            float4 pt = xyzt4[s * 64 + lane];
            const uint32_t pidx = base + (uint32_t)(s * 64 + lane);
            #pragma unroll
            for (int j = 0; j < 4; ++j) {
                float d2 = npy_d2(pt, qx[j], qy[j], qz[j], s2[j]);
                bool  v  = (d2 <= that[j]);
                uint64_t mask = __ballot((int)v);
                if (mask != 0ull) {                // scalar gate
                    if (v) {
                        uint32_t below = __builtin_amdgcn_mbcnt_hi(
                            (uint32_t)(mask >> 32),
                            __builtin_amdgcn_mbcnt_lo((uint32_t)mask, 0u));
                        uint32_t pos    = cnt[j] + below;
                        uint32_t bits   = __float_as_uint(d2);
                        uint32_t mapped = bits ^ (0x80000000u |
                                          (uint32_t)((int32_t)bits >> 31));
                        if (pos < 128u)
                            wball[(w * 4 + j) * 128 + pos] =
                                ((uint64_t)mapped << 32) | (uint64_t)pidx;
                    }
                    cnt[j] += (uint32_t)__popcll(mask);
                }
            }
        }
    }

    // ---------------- per-query selection + weights (R8-exact) ----------------
    int   myidxA[4];
    float mywgtA[4];
    #pragma unroll
    for (int j = 0; j < 4; ++j) {
        const uint64_t* wb = wball + (size_t)(w * 4 + j) * 128;
        const uint32_t c = cnt[j];
        uint64_t mykey;
        if (c <= 64u) {                            // normal path
            uint64_t k0 = (lane < (int)c) ? wb[lane] : ~0ull;
            mykey = sort64(k0, lane);
        } else {                                   // uniform fallback
            uint32_t cc = c > 128u ? 128u : c;
            uint64_t k0 = wb[lane];
            uint64_t k1 = (lane + 64 < (int)cc) ? wb[lane + 64] : ~0ull;
            k0 = sort64(k0, lane);
            k1 = sort64(k1, lane);
            uint64_t t1 = __shfl((unsigned long long)k1, lane & 15, 64);
            uint64_t km = (lane < 16) ? k0 : ((lane < 32) ? t1 : ~0ull);
            mykey = sort64(km, lane);
        }
        uint32_t mhi   = (uint32_t)(mykey >> 32);
        uint32_t rbits = (mhi & 0x80000000u) ? (mhi ^ 0x80000000u) : ~mhi;
        float    d2w   = __uint_as_float(rbits);
        myidxA[j] = (int)(uint32_t)(mykey & 0xFFFFFFFFull);
        float recip = (lane < KQ) ? (1.0f / (d2w + 1e-8f)) : 0.0f;
        float tot = recip;
        #pragma unroll
        for (int sh = 1; sh < 16; sh <<= 1) tot += __shfl_xor(tot, sh, 64);
        mywgtA[j] = recip / tot;                   // valid in lanes 0..15
    }

    // LDS reuse boundary: all waves done with xyzt4 + wbuf
    __syncthreads();

    // ---------------- Stage 2: build cat[16][384] in LDS ----------------
    const float* p2b = points2 + (size_t)b * NQ * D2Q;
    #pragma unroll
    for (int j = 0; j < 4; ++j) {
        const int qi = w * 4 + j;
        // p1 part: 128 floats, lanes 0..31
        if (lane < 32) {
            float4 p = ((const float4*)(points1 + (size_t)(qbase + j) * D1Q))[lane];
            *(float4*)&cat[qi * CATQ + lane * 4] = p;
        }
        // interp part: 256 floats, all 64 lanes; k ascending (reference order)
        float4 acc = make_float4(0.f, 0.f, 0.f, 0.f);
        #pragma unroll
        for (int k = 0; k < KQ; ++k) {
            int   kk = __builtin_amdgcn_readlane(myidxA[j], k);
            float wk = __uint_as_float((uint32_t)__builtin_amdgcn_readlane(
                           (int)__float_as_uint(mywgtA[j]), k));
            float4 row = ((const float4*)(p2b + (size_t)kk * D2Q))[lane];
            acc.x = fmaf(wk, row.x, acc.x);
            acc.y = fmaf(wk, row.y, acc.y);
            acc.z = fmaf(wk, row.z, acc.z);
            acc.w = fmaf(wk, row.w, acc.w);
        }
        *(float4*)&cat[qi * CATQ + D1Q + lane * 4] = acc;
    }
    __syncthreads();

    // ---------------- Stage 3: block GEMM cat @ Wt + bias ----------------
    const int rg = tid >> 5;              // 0..7 -> cat rows rg*2, rg*2+1
    const int o0 = (tid & 31) * 4;        // output col base
    float4 acc0 = make_float4(0.f, 0.f, 0.f, 0.f);
    float4 acc1 = make_float4(0.f, 0.f, 0.f, 0.f);

    for (int c = 0; c < 12; ++c) {
        if (c) __syncthreads();           // protect previous chunk's readers
        {
            const float4* src = (const float4*)(Wt + (size_t)c * 32 * OUTQ);
            #pragma unroll
            for (int i = 0; i < 4; ++i)
                ((float4*)Wl)[tid + 256 * i] = src[tid + 256 * i];
        }
        __syncthreads();

        const int kb = c * 32;
        #pragma unroll
        for (int k4 = 0; k4 < 8; ++k4) {
            const float* wb = Wl + (k4 * 4) * OUTQ + o0;
            float4 w0 = *(const float4*)(wb + 0 * OUTQ);
            float4 w1 = *(const float4*)(wb + 1 * OUTQ);
            float4 w2 = *(const float4*)(wb + 2 * OUTQ);
            float4 w3 = *(const float4*)(wb + 3 * OUTQ);
            float4 a0 = *(const float4*)&cat[(rg * 2 + 0) * CATQ + kb + k4 * 4];
            float4 a1 = *(const float4*)&cat[(rg * 2 + 1) * CATQ + kb + k4 * 4];
            fma4(acc0, a0.x, w0); fma4(acc0, a0.y, w1);
            fma4(acc0, a0.z, w2); fma4(acc0, a0.w, w3);
            fma4(acc1, a1.x, w0); fma4(acc1, a1.y, w1);
            fma4(acc1, a1.z, w2); fma4(acc1, a1.w, w3);
        }
    }

    {
        float4 bv = *(const float4*)(bias + o0);
        acc0.x += bv.x; acc0.y += bv.y; acc0.z += bv.z; acc0.w += bv.w;
        acc1.x += bv.x; acc1.y += bv.y; acc1.z += bv.z; acc1.w += bv.w;
        const int q0 = blockIdx.x * 16 + rg * 2;
        *(float4*)&out[(size_t)(q0 + 0) * OUTQ + o0] = acc0;
        *(float4*)&out[(size_t)(q0 + 1) * OUTQ + o0] = acc1;
    }
}

// ---------------------------------------------------------------------------
// Launch
// ---------------------------------------------------------------------------
extern "C" void kernel_launch(void* const* d_in, const int* in_sizes, int n_in,
                              void* d_out, int out_size, void* d_ws, size_t ws_size,
                              hipStream_t stream) {
    const float* xyz1    = (const float*)d_in[0];
    const float* xyz2    = (const float*)d_in[1];
    const float* points1 = (const float*)d_in[2];
    const float* points2 = (const float*)d_in[3];
    const float* W       = (const float*)d_in[4];
    const float* bias    = (const float*)d_in[5];

    float* wsf  = (float*)d_ws;
    float* Wt   = wsf;                         // 384*128 = 49152 floats
    float4* xyz1n = (float4*)(wsf + 49152);    // 16384 float4

    prep_kernel<<<192, 256, 0, stream>>>(W, Wt, xyz1, xyz1n);
    fused_kernel<<<(BQ * NQ) / 16, 256, 0, stream>>>(
        xyz1n, xyz2, points1, points2, Wt, bias, (float*)d_out);
}